// Round 1
// baseline (326.122 us; speedup 1.0000x reference)
//
#include <hip/hip_runtime.h>
#include <cstdint>

#define NTOT 4096   // 2b rows
#define BHALF 2048  // b
#define D1 4096
#define D2 2048
#define TT 32       // 4096/128 tiles per dim
#define NTILES 528  // TT*(TT+1)/2

typedef __attribute__((ext_vector_type(4))) float f32x4;
typedef __attribute__((ext_vector_type(4))) int i32x4;
typedef __attribute__((ext_vector_type(8))) int i32x8;

// async 16B global->LDS DMA (wave-uniform LDS base + lane*16 scatter)
__device__ __forceinline__ void glds16(const uint8_t* g, uint8_t* l) {
    __builtin_amdgcn_global_load_lds(
        (const __attribute__((address_space(1))) void*)(uintptr_t)g,
        (__attribute__((address_space(3))) void*)(uint32_t)(uintptr_t)l,
        16, 0, 0);
}

// raw LDS b128 read, opaque to the compiler's waitcnt insertion
__device__ __forceinline__ i32x4 ldsr(uint32_t addr) {
    i32x4 r;
    asm volatile("ds_read_b128 %0, %1" : "=v"(r) : "v"(addr));
    return r;
}

// e4m3fn decode (for colsum only; data never near NaN/448)
__device__ __forceinline__ float fp8dec(unsigned b) {
    unsigned e = (b >> 3) & 15u, m = b & 7u;
    float v = e ? __uint_as_float(((e + 120u) << 23) | (m << 20))
                : (float)m * 0.001953125f;   // subnormal: m * 2^-9
    return (b & 128u) ? -v : v;
}

// ---------------- prep: per-row sumsq (fp32) + fp8 e4m3 convert ----------------
// One block per row, handling BOTH tensors (halves dispatch count vs 2-row split;
// per-thread accumulation order identical to previous version -> bit-exact sq).
__global__ void prep_kernel(const float* __restrict__ z1s, const float* __restrict__ z1t,
                            const float* __restrict__ z2s, const float* __restrict__ z2t,
                            float* __restrict__ sq1, float* __restrict__ sq2,
                            uint8_t* __restrict__ t1f8, uint8_t* __restrict__ t2f8,
                            float* __restrict__ s1, float* __restrict__ s2) {
    int row = blockIdx.x;
    int tid = threadIdx.x;
    if (row == 0) { for (int i = tid; i < 4096; i += 256) s1[i] = 0.f; }
    if (row == 1) { for (int i = tid; i < 2048; i += 256) s2[i] = 0.f; }
    bool lower = row < BHALF;
    const float* src1 = lower ? z1s + (size_t)row * D1 : z1t + (size_t)(row - BHALF) * D1;
    const float* src2 = lower ? z2s + (size_t)row * D2 : z2t + (size_t)(row - BHALF) * D2;
    uint8_t* dst1 = t1f8 + (size_t)row * D1;
    uint8_t* dst2 = t2f8 + (size_t)row * D2;
    float a1 = 0.f, a2 = 0.f;
    {
        const float4* s4 = (const float4*)src1;
        for (int i = tid; i < (D1 >> 3); i += 256) {
            float4 v0 = s4[2 * i], v1 = s4[2 * i + 1];
            a1 += v0.x * v0.x + v0.y * v0.y + v0.z * v0.z + v0.w * v0.w;
            a1 += v1.x * v1.x + v1.y * v1.y + v1.z * v1.z + v1.w * v1.w;
            int w0 = __builtin_amdgcn_cvt_pk_fp8_f32(v0.x, v0.y, 0, 0);
            w0 = __builtin_amdgcn_cvt_pk_fp8_f32(v0.z, v0.w, w0, 1);
            int w1 = __builtin_amdgcn_cvt_pk_fp8_f32(v1.x, v1.y, 0, 0);
            w1 = __builtin_amdgcn_cvt_pk_fp8_f32(v1.z, v1.w, w1, 1);
            ((uint2*)dst1)[i] = uint2{(unsigned)w0, (unsigned)w1};
        }
    }
    {
        const float4* s4 = (const float4*)src2;
        for (int i = tid; i < (D2 >> 3); i += 256) {
            float4 v0 = s4[2 * i], v1 = s4[2 * i + 1];
            a2 += v0.x * v0.x + v0.y * v0.y + v0.z * v0.z + v0.w * v0.w;
            a2 += v1.x * v1.x + v1.y * v1.y + v1.z * v1.z + v1.w * v1.w;
            int w0 = __builtin_amdgcn_cvt_pk_fp8_f32(v0.x, v0.y, 0, 0);
            w0 = __builtin_amdgcn_cvt_pk_fp8_f32(v0.z, v0.w, w0, 1);
            int w1 = __builtin_amdgcn_cvt_pk_fp8_f32(v1.x, v1.y, 0, 0);
            w1 = __builtin_amdgcn_cvt_pk_fp8_f32(v1.z, v1.w, w1, 1);
            ((uint2*)dst2)[i] = uint2{(unsigned)w0, (unsigned)w1};
        }
    }
    for (int o = 32; o; o >>= 1) {
        a1 += __shfl_down(a1, o);
        a2 += __shfl_down(a2, o);
    }
    __shared__ float sh[2][4];
    int lane = tid & 63, w = tid >> 6;
    if (lane == 0) { sh[0][w] = a1; sh[1][w] = a2; }
    __syncthreads();
    if (tid == 0) {
        sq1[row] = sh[0][0] + sh[0][1] + sh[0][2] + sh[0][3];
        sq2[row] = sh[1][0] + sh[1][1] + sh[1][2] + sh[1][3];
    }
}

// ---------------- column sums from fp8 copies (bandwidth term only) ----------------
// uint4-vectorized (16B/lane, G13): 4x fewer load instrs than uchar4 version.
// Per-column partial = same 64-row stripe grouping as before -> bit-identical s1/s2.
__global__ void colsum_fp8_kernel(const uint8_t* __restrict__ t1f8,
                                  const uint8_t* __restrict__ t2f8,
                                  float* __restrict__ s1, float* __restrict__ s2) {
    int bid = blockIdx.x;
    int tid = threadIdx.x;
    const uint8_t* base;
    float* s;
    int d, stripe, col;
    if (bid < 64) {              // D1: one 64-row stripe per block, 256 thr x 16 cols
        base = t1f8; s = s1; d = D1;
        stripe = bid; col = tid * 16;
    } else {                     // D2: two 64-row stripes per block, 128 thr x 16 cols
        base = t2f8; s = s2; d = D2;
        int lb = bid - 64;       // 0..31
        stripe = lb * 2 + (tid >> 7);
        col = (tid & 127) * 16;
    }
    int r0 = stripe * 64;
    const uint8_t* p = base + (size_t)r0 * d + col;
    float a[16];
#pragma unroll
    for (int i = 0; i < 16; ++i) a[i] = 0.f;
#pragma unroll 4
    for (int r = 0; r < 64; ++r) {
        uint4 u = *(const uint4*)(p + (size_t)r * d);
        unsigned w0 = u.x, w1 = u.y, w2 = u.z, w3 = u.w;
#pragma unroll
        for (int k = 0; k < 4; ++k) {
            a[0 + k]  += fp8dec((w0 >> (8 * k)) & 255u);
            a[4 + k]  += fp8dec((w1 >> (8 * k)) & 255u);
            a[8 + k]  += fp8dec((w2 >> (8 * k)) & 255u);
            a[12 + k] += fp8dec((w3 >> (8 * k)) & 255u);
        }
    }
#pragma unroll
    for (int i = 0; i < 16; ++i) atomicAdd(&s[col + i], a[i]);
}

// ---------------- finalize: bandwidth constants + loss bias ----------------
__global__ void finalize_kernel(const float* __restrict__ s1, const float* __restrict__ s2,
                                const float* __restrict__ sq1, const float* __restrict__ sq2,
                                float* __restrict__ acc, float* __restrict__ out) {
    int tid = threadIdx.x;
    float a1 = 0.f, a2 = 0.f, q1 = 0.f, q2 = 0.f;
    for (int i = tid; i < 4096; i += 256) { float v = s1[i]; a1 += v * v; q1 += sq1[i]; q2 += sq2[i]; }
    for (int i = tid; i < 2048; i += 256) { float v = s2[i]; a2 += v * v; }
    for (int o = 32; o; o >>= 1) {
        a1 += __shfl_down(a1, o); a2 += __shfl_down(a2, o);
        q1 += __shfl_down(q1, o); q2 += __shfl_down(q2, o);
    }
    __shared__ float sh[4][4];
    int lane = tid & 63, w = tid >> 6;
    if (lane == 0) { sh[0][w] = a1; sh[1][w] = a2; sh[2][w] = q1; sh[3][w] = q2; }
    __syncthreads();
    if (tid == 0) {
        double ss1 = (double)sh[0][0] + sh[0][1] + sh[0][2] + sh[0][3];
        double ss2 = (double)sh[1][0] + sh[1][1] + sh[1][2] + sh[1][3];
        double t1 = (double)sh[2][0] + sh[2][1] + sh[2][2] + sh[2][3];
        double t2 = (double)sh[3][0] + sh[3][1] + sh[3][2] + sh[3][3];
        double S1 = 2.0 * (double)NTOT * t1 - 2.0 * ss1;
        double S2 = 2.0 * (double)NTOT * t2 - 2.0 * ss2;
        const double L2E = 1.4426950408889634;
        double nn = (double)NTOT * (double)(NTOT - 1);
        acc[2] = (float)(nn * L2E / (4.0 * S1));
        acc[3] = (float)(nn * L2E / (4.0 * S2));
        out[0] = 2.0f / (float)(BHALF - 1);
    }
}

// ---------------- pipelined MX-fp8 GEMM K-loop, cluster-interleaved ----------------
// v2: the old {16 ds_read -> lgkmcnt(0) -> 16 MFMA} body alternated an LDS storm
// (~2050 cy/CU/kstep incl. conflicts) with an MFMA burst (~1104 cy/CU/kstep) with
// zero overlap -> measured MfmaUtil 18.4% == the no-overlap prediction.
// Now: reads issue in 2 groups (B01,A01 | B23,A23); MFMAs run in 3 clusters gated
// by counted lgkmcnt(8)/(4)/(0) so cluster 0 computes while group 2 is still in
// the LDS pipe (T3/T4). setprio(1) wraps each cluster (T5 pays once phases split).
// WAR barrier moved directly after lgkmcnt(0): the final 8 MFMAs (register-only)
// run in the barrier shadow, overlapping other waves' next-step prefetch/reads.
// sched_barrier(0) after each wait: hipcc hoists register-only MFMA past inline-asm
// waitcnt despite "memory" clobber (rule #18).
// Accumulation order per acc element unchanged -> bit-identical results.
__device__ __forceinline__ void gemm_mx_pipe(const uint8_t* __restrict__ ga,
                                             const uint8_t* __restrict__ gb,
                                             int d,
                                             uint8_t* A0, uint8_t* B0,
                                             uint8_t* A1, uint8_t* B1,
                                             f32x4 (&acc)[4][4], int wv, int lane,
                                             int wm, int wn, int lm, int quad) {
    int nsteps = d >> 7;
    int rsub = lane >> 3;
    int ql = (lane & 7) ^ rsub;          // swizzled source chunk
    const uint8_t* pa = ga + (size_t)(wv * 32 + rsub) * d + ql * 16;
    const uint8_t* pb = gb + (size_t)(wv * 32 + rsub) * d + ql * 16;
    uint8_t* dA[2] = { A0 + wv * 4096, A1 + wv * 4096 };
    uint8_t* dB[2] = { B0 + wv * 4096, B1 + wv * 4096 };
    uint32_t baseA[2] = { (uint32_t)(uintptr_t)A0, (uint32_t)(uintptr_t)A1 };
    uint32_t baseB[2] = { (uint32_t)(uintptr_t)B0, (uint32_t)(uintptr_t)B1 };
    int s0 = ((2 * quad) ^ (lm & 7)) * 16;
    int s1 = ((2 * quad + 1) ^ (lm & 7)) * 16;
    uint32_t offA[4], offB[4];
#pragma unroll
    for (int i = 0; i < 4; ++i) {
        offA[i] = (uint32_t)((wm * 64 + i * 16 + lm) * 128);
        offB[i] = (uint32_t)((wn * 64 + i * 16 + lm) * 128);
    }
    // prime buffer 0 (k=0)
#pragma unroll
    for (int i = 0; i < 4; ++i) {
        glds16(pa + (size_t)i * 8 * d, dA[0] + i * 1024);
        glds16(pb + (size_t)i * 8 * d, dB[0] + i * 1024);
    }
    for (int k = 0; k < nsteps; ++k) {
        int cur = k & 1, nxt = cur ^ 1;
        size_t koff = (size_t)((k + 1 < nsteps) ? (k + 1) : 0) << 7;
#pragma unroll
        for (int i = 0; i < 4; ++i) {
            glds16(pa + koff + (size_t)i * 8 * d, dA[nxt] + i * 1024);
            glds16(pb + koff + (size_t)i * 8 * d, dB[nxt] + i * 1024);
        }
        asm volatile("s_waitcnt vmcnt(8)\n\ts_barrier" ::: "memory");
        // issue group 1: B frag 0,1 + A frag 0,1 (oldest 8)
        i32x4 b00 = ldsr(baseB[cur] + offB[0] + s0), b01 = ldsr(baseB[cur] + offB[0] + s1);
        i32x4 b10 = ldsr(baseB[cur] + offB[1] + s0), b11 = ldsr(baseB[cur] + offB[1] + s1);
        i32x4 a00 = ldsr(baseA[cur] + offA[0] + s0), a01 = ldsr(baseA[cur] + offA[0] + s1);
        i32x4 a10 = ldsr(baseA[cur] + offA[1] + s0), a11 = ldsr(baseA[cur] + offA[1] + s1);
        // issue group 2: B frag 2,3 + A frag 2,3
        i32x4 b20 = ldsr(baseB[cur] + offB[2] + s0), b21 = ldsr(baseB[cur] + offB[2] + s1);
        i32x4 b30 = ldsr(baseB[cur] + offB[3] + s0), b31 = ldsr(baseB[cur] + offB[3] + s1);
        i32x4 a20 = ldsr(baseA[cur] + offA[2] + s0), a21 = ldsr(baseA[cur] + offA[2] + s1);
        i32x4 a30 = ldsr(baseA[cur] + offA[3] + s0), a31 = ldsr(baseA[cur] + offA[3] + s1);
        union F { i32x4 h[2]; i32x8 v; };
        F ua0, ua1, ua2, ua3, ub0, ub1, ub2, ub3;
        // ---- cluster 0: needs group 1 only (8 in flight = group 2) ----
        asm volatile("s_waitcnt lgkmcnt(8)"
                     : "+v"(b00), "+v"(b01), "+v"(b10), "+v"(b11),
                       "+v"(a00), "+v"(a01), "+v"(a10), "+v"(a11));
        __builtin_amdgcn_sched_barrier(0);
        ub0.h[0] = b00; ub0.h[1] = b01; ub1.h[0] = b10; ub1.h[1] = b11;
        ua0.h[0] = a00; ua0.h[1] = a01; ua1.h[0] = a10; ua1.h[1] = a11;
        __builtin_amdgcn_s_setprio(1);
        acc[0][0] = __builtin_amdgcn_mfma_scale_f32_16x16x128_f8f6f4(ua0.v, ub0.v, acc[0][0], 0, 0, 0, 0x7F7F7F7F, 0, 0x7F7F7F7F);
        acc[0][1] = __builtin_amdgcn_mfma_scale_f32_16x16x128_f8f6f4(ua0.v, ub1.v, acc[0][1], 0, 0, 0, 0x7F7F7F7F, 0, 0x7F7F7F7F);
        acc[1][0] = __builtin_amdgcn_mfma_scale_f32_16x16x128_f8f6f4(ua1.v, ub0.v, acc[1][0], 0, 0, 0, 0x7F7F7F7F, 0, 0x7F7F7F7F);
        acc[1][1] = __builtin_amdgcn_mfma_scale_f32_16x16x128_f8f6f4(ua1.v, ub1.v, acc[1][1], 0, 0, 0, 0x7F7F7F7F, 0, 0x7F7F7F7F);
        __builtin_amdgcn_s_setprio(0);
        // ---- cluster 1: + B frag 2,3 (4 in flight = A frag 2,3) ----
        asm volatile("s_waitcnt lgkmcnt(4)"
                     : "+v"(b20), "+v"(b21), "+v"(b30), "+v"(b31));
        __builtin_amdgcn_sched_barrier(0);
        ub2.h[0] = b20; ub2.h[1] = b21; ub3.h[0] = b30; ub3.h[1] = b31;
        __builtin_amdgcn_s_setprio(1);
        acc[0][2] = __builtin_amdgcn_mfma_scale_f32_16x16x128_f8f6f4(ua0.v, ub2.v, acc[0][2], 0, 0, 0, 0x7F7F7F7F, 0, 0x7F7F7F7F);
        acc[0][3] = __builtin_amdgcn_mfma_scale_f32_16x16x128_f8f6f4(ua0.v, ub3.v, acc[0][3], 0, 0, 0, 0x7F7F7F7F, 0, 0x7F7F7F7F);
        acc[1][2] = __builtin_amdgcn_mfma_scale_f32_16x16x128_f8f6f4(ua1.v, ub2.v, acc[1][2], 0, 0, 0, 0x7F7F7F7F, 0, 0x7F7F7F7F);
        acc[1][3] = __builtin_amdgcn_mfma_scale_f32_16x16x128_f8f6f4(ua1.v, ub3.v, acc[1][3], 0, 0, 0, 0x7F7F7F7F, 0, 0x7F7F7F7F);
        __builtin_amdgcn_s_setprio(0);
        // ---- all reads landed: release the buffer (WAR barrier), then cluster 2/3
        // runs register-only in the barrier shadow ----
        asm volatile("s_waitcnt lgkmcnt(0)"
                     : "+v"(a20), "+v"(a21), "+v"(a30), "+v"(a31));
        __builtin_amdgcn_sched_barrier(0);
        asm volatile("s_barrier" ::: "memory");
        __builtin_amdgcn_sched_barrier(0);
        ua2.h[0] = a20; ua2.h[1] = a21; ua3.h[0] = a30; ua3.h[1] = a31;
        __builtin_amdgcn_s_setprio(1);
        acc[2][0] = __builtin_amdgcn_mfma_scale_f32_16x16x128_f8f6f4(ua2.v, ub0.v, acc[2][0], 0, 0, 0, 0x7F7F7F7F, 0, 0x7F7F7F7F);
        acc[2][1] = __builtin_amdgcn_mfma_scale_f32_16x16x128_f8f6f4(ua2.v, ub1.v, acc[2][1], 0, 0, 0, 0x7F7F7F7F, 0, 0x7F7F7F7F);
        acc[2][2] = __builtin_amdgcn_mfma_scale_f32_16x16x128_f8f6f4(ua2.v, ub2.v, acc[2][2], 0, 0, 0, 0x7F7F7F7F, 0, 0x7F7F7F7F);
        acc[2][3] = __builtin_amdgcn_mfma_scale_f32_16x16x128_f8f6f4(ua2.v, ub3.v, acc[2][3], 0, 0, 0, 0x7F7F7F7F, 0, 0x7F7F7F7F);
        acc[3][0] = __builtin_amdgcn_mfma_scale_f32_16x16x128_f8f6f4(ua3.v, ub0.v, acc[3][0], 0, 0, 0, 0x7F7F7F7F, 0, 0x7F7F7F7F);
        acc[3][1] = __builtin_amdgcn_mfma_scale_f32_16x16x128_f8f6f4(ua3.v, ub1.v, acc[3][1], 0, 0, 0, 0x7F7F7F7F, 0, 0x7F7F7F7F);
        acc[3][2] = __builtin_amdgcn_mfma_scale_f32_16x16x128_f8f6f4(ua3.v, ub2.v, acc[3][2], 0, 0, 0, 0x7F7F7F7F, 0, 0x7F7F7F7F);
        acc[3][3] = __builtin_amdgcn_mfma_scale_f32_16x16x128_f8f6f4(ua3.v, ub3.v, acc[3][3], 0, 0, 0, 0x7F7F7F7F, 0, 0x7F7F7F7F);
        __builtin_amdgcn_s_setprio(0);
    }
}

// ---------------- fused dual-GEMM + kernel epilogue (no Gram materialization) ----
__global__ __launch_bounds__(256, 2) void jmmd_fused(
    const uint8_t* __restrict__ t1f8, const uint8_t* __restrict__ t2f8,
    const float* __restrict__ sq1, const float* __restrict__ sq2,
    const float* __restrict__ cv, float* __restrict__ out) {
    __shared__ alignas(16) uint8_t smem[4][16384];   // A0,B0,A1,B1
    __shared__ float sqi1[128], sqj1[128], sqi2[128], sqj2[128];
    __shared__ float red[4];
    int tid = threadIdx.x;
    int ti = 0, r = blockIdx.x;
    while (r >= TT - ti) { r -= TT - ti; ++ti; }
    int tj = ti + r;
    int i0 = ti * 128, j0 = tj * 128;
    if (tid < 128) {
        sqi1[tid] = sq1[i0 + tid]; sqj1[tid] = sq1[j0 + tid];
        sqi2[tid] = sq2[i0 + tid]; sqj2[tid] = sq2[j0 + tid];
    }
    int lane = tid & 63, wv = tid >> 6;
    int wm = wv >> 1, wn = wv & 1, lm = lane & 15, quad = lane >> 4;
    f32x4 acc1[4][4] = {};
    f32x4 acc2[4][4] = {};
    gemm_mx_pipe(t1f8 + (size_t)i0 * D1, t1f8 + (size_t)j0 * D1, D1,
                 smem[0], smem[1], smem[2], smem[3], acc1, wv, lane, wm, wn, lm, quad);
    // drain dummy prefetch + sync before re-priming the same buffers
    asm volatile("s_waitcnt vmcnt(0)\n\ts_barrier" ::: "memory");
    gemm_mx_pipe(t2f8 + (size_t)i0 * D2, t2f8 + (size_t)j0 * D2, D2,
                 smem[0], smem[1], smem[2], smem[3], acc2, wv, lane, wm, wn, lm, quad);
    float c1 = cv[0], c2 = cv[1];
    float local = 0.f;
    bool diag = (ti == tj);
#pragma unroll
    for (int mi = 0; mi < 4; ++mi) {
        int rbase = wm * 64 + mi * 16 + quad * 4;
#pragma unroll
        for (int ni = 0; ni < 4; ++ni) {
            int col = wn * 64 + ni * 16 + lm;
            float sb1 = sqj1[col], sb2 = sqj2[col];
#pragma unroll
            for (int rr = 0; rr < 4; ++rr) {
                int row = rbase + rr;
                float l2a = fmaxf(sqi1[row] + sb1 - 2.f * acc1[mi][ni][rr], 0.f);
                float l2b = fmaxf(sqi2[row] + sb2 - 2.f * acc2[mi][ni][rr], 0.f);
                float t1 = __builtin_amdgcn_exp2f(-l2a * c1);
                float k1 = t1; float u1 = t1 * t1; k1 += u1; u1 *= u1; k1 += u1; u1 *= u1; k1 += u1; u1 *= u1; k1 += u1;
                float t2 = __builtin_amdgcn_exp2f(-l2b * c2);
                float k2 = t2; float u2 = t2 * t2; k2 += u2; u2 *= u2; k2 += u2; u2 *= u2; k2 += u2; u2 *= u2; k2 += u2;
                float v = k1 * k2;
                if (diag && (row == col)) v = 0.f;
                local += v;
            }
        }
    }
    for (int o = 32; o; o >>= 1) local += __shfl_down(local, o);
    if (lane == 0) red[wv] = local;
    __syncthreads();
    if (tid == 0) {
        bool same = (i0 < BHALF) == (j0 < BHALF);
        float w = same ? (1.0f / ((float)BHALF * (float)(BHALF - 1)))
                       : (-1.0f / ((float)BHALF * (float)BHALF));
        if (!diag) w *= 2.f;
        atomicAdd(out, (red[0] + red[1] + red[2] + red[3]) * w);
    }
}

extern "C" void kernel_launch(void* const* d_in, const int* in_sizes, int n_in,
                              void* d_out, int out_size, void* d_ws, size_t ws_size,
                              hipStream_t stream) {
    const float* z1s = (const float*)d_in[0];
    const float* z1t = (const float*)d_in[1];
    const float* z2s = (const float*)d_in[2];
    const float* z2t = (const float*)d_in[3];
    float* out = (float*)d_out;

    float* ws = (float*)d_ws;
    float* sq1 = ws;              // 4096
    float* sq2 = ws + 4096;       // 4096
    float* s1  = ws + 8192;       // 4096
    float* s2  = ws + 12288;      // 2048
    float* acc = ws + 14336;      // [2]=c1 [3]=c2
    uint8_t* t1f8 = (uint8_t*)(ws + 14344);            // 16B-aligned
    uint8_t* t2f8 = t1f8 + (size_t)NTOT * D1;

    prep_kernel<<<4096, 256, 0, stream>>>(z1s, z1t, z2s, z2t, sq1, sq2, t1f8, t2f8, s1, s2);
    colsum_fp8_kernel<<<96, 256, 0, stream>>>(t1f8, t2f8, s1, s2);
    finalize_kernel<<<1, 256, 0, stream>>>(s1, s2, sq1, sq2, acc, out);
    jmmd_fused<<<NTILES, 256, 0, stream>>>(t1f8, t2f8, sq1, sq2, acc + 2, out);
}

// Round 2
// 270.705 us; speedup vs baseline: 1.2047x; 1.2047x over previous
//
#include <hip/hip_runtime.h>
#include <cstdint>

#define NTOT 4096   // 2b rows
#define BHALF 2048  // b
#define D1 4096
#define D2 2048
#define TT 32       // 4096/128 tiles per dim
#define NTILES 528  // TT*(TT+1)/2

typedef __attribute__((ext_vector_type(4))) float f32x4;
typedef __attribute__((ext_vector_type(4))) int i32x4;
typedef __attribute__((ext_vector_type(8))) int i32x8;

// async 16B global->LDS DMA (wave-uniform LDS base + lane*16 scatter)
__device__ __forceinline__ void glds16(const uint8_t* g, uint8_t* l) {
    __builtin_amdgcn_global_load_lds(
        (const __attribute__((address_space(1))) void*)(uintptr_t)g,
        (__attribute__((address_space(3))) void*)(uint32_t)(uintptr_t)l,
        16, 0, 0);
}

// raw LDS b128 read, opaque to the compiler's waitcnt insertion
__device__ __forceinline__ i32x4 ldsr(uint32_t addr) {
    i32x4 r;
    asm volatile("ds_read_b128 %0, %1" : "=v"(r) : "v"(addr));
    return r;
}

// e4m3fn decode (for colsum only; data never near NaN/448)
__device__ __forceinline__ float fp8dec(unsigned b) {
    unsigned e = (b >> 3) & 15u, m = b & 7u;
    float v = e ? __uint_as_float(((e + 120u) << 23) | (m << 20))
                : (float)m * 0.001953125f;   // subnormal: m * 2^-9
    return (b & 128u) ? -v : v;
}

// ---------------- prep: per-row sumsq (fp32) + fp8 e4m3 convert ----------------
// R2: reverted to the round-0 8192-block form (one block per row per tensor) —
// the 4096-block merged version regressed total by tens of µs (less TLP on a
// latency-bound kernel). Bit-exact per-thread accumulation order.
__global__ void prep_kernel(const float* __restrict__ z1s, const float* __restrict__ z1t,
                            const float* __restrict__ z2s, const float* __restrict__ z2t,
                            float* __restrict__ sq1, float* __restrict__ sq2,
                            uint8_t* __restrict__ t1f8, uint8_t* __restrict__ t2f8,
                            float* __restrict__ s1, float* __restrict__ s2) {
    int bid = blockIdx.x;
    int tid = threadIdx.x;
    if (bid == 0) { for (int i = tid; i < 4096; i += 256) s1[i] = 0.f; }
    if (bid == 1) { for (int i = tid; i < 2048; i += 256) s2[i] = 0.f; }
    int which = bid >> 12;
    int row = bid & 4095;
    int d = which ? D2 : D1;
    const float* s_ = which ? z2s : z1s;
    const float* t_ = which ? z2t : z1t;
    const float* src = (row < BHALF) ? s_ + (size_t)row * d : t_ + (size_t)(row - BHALF) * d;
    uint8_t* dst = (which ? t2f8 : t1f8) + (size_t)row * d;
    float* sq = which ? sq2 : sq1;
    const float4* src4 = (const float4*)src;
    float a = 0.f;
    int n8 = d >> 3;
    for (int i = tid; i < n8; i += 256) {
        float4 v0 = src4[2 * i], v1 = src4[2 * i + 1];
        a += v0.x * v0.x + v0.y * v0.y + v0.z * v0.z + v0.w * v0.w;
        a += v1.x * v1.x + v1.y * v1.y + v1.z * v1.z + v1.w * v1.w;
        int w0 = __builtin_amdgcn_cvt_pk_fp8_f32(v0.x, v0.y, 0, 0);
        w0 = __builtin_amdgcn_cvt_pk_fp8_f32(v0.z, v0.w, w0, 1);
        int w1 = __builtin_amdgcn_cvt_pk_fp8_f32(v1.x, v1.y, 0, 0);
        w1 = __builtin_amdgcn_cvt_pk_fp8_f32(v1.z, v1.w, w1, 1);
        ((uint2*)dst)[i] = uint2{(unsigned)w0, (unsigned)w1};
    }
    for (int o = 32; o; o >>= 1) a += __shfl_down(a, o);
    __shared__ float sh[4];
    int lane = tid & 63, w = tid >> 6;
    if (lane == 0) sh[w] = a;
    __syncthreads();
    if (tid == 0) sq[row] = sh[0] + sh[1] + sh[2] + sh[3];
}

// ---------------- column sums from fp8 copies (bandwidth term only) ----------------
// R2: reverted to the round-0 384-block form (96-block version regressed).
__global__ void colsum_fp8_kernel(const uint8_t* __restrict__ t1f8,
                                  const uint8_t* __restrict__ t2f8,
                                  float* __restrict__ s1, float* __restrict__ s2) {
    int bid = blockIdx.x;
    int which = bid >= 256;
    int local = which ? bid - 256 : bid;
    int d = which ? D2 : D1;
    int colchunks = d >> 10;
    int cb = local % colchunks, rb = local / colchunks;
    const uint8_t* base = which ? t2f8 : t1f8;
    float* s = which ? s2 : s1;
    int col = (cb << 10) + threadIdx.x * 4;
    int r0 = rb * 64;
    float a0 = 0.f, a1 = 0.f, a2 = 0.f, a3 = 0.f;
    const uint8_t* p = base + (size_t)r0 * d + col;
#pragma unroll 4
    for (int r = 0; r < 64; ++r) {
        uchar4 u = *(const uchar4*)(p + (size_t)r * d);
        a0 += fp8dec(u.x); a1 += fp8dec(u.y); a2 += fp8dec(u.z); a3 += fp8dec(u.w);
    }
    atomicAdd(&s[col], a0); atomicAdd(&s[col + 1], a1);
    atomicAdd(&s[col + 2], a2); atomicAdd(&s[col + 3], a3);
}

// ---------------- finalize: bandwidth constants + loss bias ----------------
__global__ void finalize_kernel(const float* __restrict__ s1, const float* __restrict__ s2,
                                const float* __restrict__ sq1, const float* __restrict__ sq2,
                                float* __restrict__ acc, float* __restrict__ out) {
    int tid = threadIdx.x;
    float a1 = 0.f, a2 = 0.f, q1 = 0.f, q2 = 0.f;
    for (int i = tid; i < 4096; i += 256) { float v = s1[i]; a1 += v * v; q1 += sq1[i]; q2 += sq2[i]; }
    for (int i = tid; i < 2048; i += 256) { float v = s2[i]; a2 += v * v; }
    for (int o = 32; o; o >>= 1) {
        a1 += __shfl_down(a1, o); a2 += __shfl_down(a2, o);
        q1 += __shfl_down(q1, o); q2 += __shfl_down(q2, o);
    }
    __shared__ float sh[4][4];
    int lane = tid & 63, w = tid >> 6;
    if (lane == 0) { sh[0][w] = a1; sh[1][w] = a2; sh[2][w] = q1; sh[3][w] = q2; }
    __syncthreads();
    if (tid == 0) {
        double ss1 = (double)sh[0][0] + sh[0][1] + sh[0][2] + sh[0][3];
        double ss2 = (double)sh[1][0] + sh[1][1] + sh[1][2] + sh[1][3];
        double t1 = (double)sh[2][0] + sh[2][1] + sh[2][2] + sh[2][3];
        double t2 = (double)sh[3][0] + sh[3][1] + sh[3][2] + sh[3][3];
        double S1 = 2.0 * (double)NTOT * t1 - 2.0 * ss1;
        double S2 = 2.0 * (double)NTOT * t2 - 2.0 * ss2;
        const double L2E = 1.4426950408889634;
        double nn = (double)NTOT * (double)(NTOT - 1);
        acc[2] = (float)(nn * L2E / (4.0 * S1));
        acc[3] = (float)(nn * L2E / (4.0 * S2));
        out[0] = 2.0f / (float)(BHALF - 1);
    }
}

// ---------------- pipelined MX-fp8 GEMM K-loop, cluster-interleaved ----------------
// R2 theory: jmmd ran at ONE block/CU (Occupancy 13% = 4 waves/CU = 1 wave/SIMD)
// because static LDS was 68096 B and 2x68096 > 128 KiB schedulable pool. With one
// wave/SIMD every phase is serial -> MfmaUtil == MFMA/serial-path = 550/2740 = 20%
// (matches 19% measured). Fix is LDS diet to exactly 64 KiB (see jmmd_fused) so two
// independent blocks co-reside and overlap each other's stalls (m114-style).
// Loop body itself unchanged from the R1-validated cluster-interleaved form.
__device__ __forceinline__ void gemm_mx_pipe(const uint8_t* __restrict__ ga,
                                             const uint8_t* __restrict__ gb,
                                             int d,
                                             uint8_t* A0, uint8_t* B0,
                                             uint8_t* A1, uint8_t* B1,
                                             f32x4 (&acc)[4][4], int wv, int lane,
                                             int wm, int wn, int lm, int quad) {
    int nsteps = d >> 7;
    int rsub = lane >> 3;
    int ql = (lane & 7) ^ rsub;          // swizzled source chunk
    const uint8_t* pa = ga + (size_t)(wv * 32 + rsub) * d + ql * 16;
    const uint8_t* pb = gb + (size_t)(wv * 32 + rsub) * d + ql * 16;
    uint8_t* dA[2] = { A0 + wv * 4096, A1 + wv * 4096 };
    uint8_t* dB[2] = { B0 + wv * 4096, B1 + wv * 4096 };
    uint32_t baseA[2] = { (uint32_t)(uintptr_t)A0, (uint32_t)(uintptr_t)A1 };
    uint32_t baseB[2] = { (uint32_t)(uintptr_t)B0, (uint32_t)(uintptr_t)B1 };
    int s0 = ((2 * quad) ^ (lm & 7)) * 16;
    int s1 = ((2 * quad + 1) ^ (lm & 7)) * 16;
    uint32_t offA[4], offB[4];
#pragma unroll
    for (int i = 0; i < 4; ++i) {
        offA[i] = (uint32_t)((wm * 64 + i * 16 + lm) * 128);
        offB[i] = (uint32_t)((wn * 64 + i * 16 + lm) * 128);
    }
    // prime buffer 0 (k=0)
#pragma unroll
    for (int i = 0; i < 4; ++i) {
        glds16(pa + (size_t)i * 8 * d, dA[0] + i * 1024);
        glds16(pb + (size_t)i * 8 * d, dB[0] + i * 1024);
    }
    for (int k = 0; k < nsteps; ++k) {
        int cur = k & 1, nxt = cur ^ 1;
        size_t koff = (size_t)((k + 1 < nsteps) ? (k + 1) : 0) << 7;
#pragma unroll
        for (int i = 0; i < 4; ++i) {
            glds16(pa + koff + (size_t)i * 8 * d, dA[nxt] + i * 1024);
            glds16(pb + koff + (size_t)i * 8 * d, dB[nxt] + i * 1024);
        }
        asm volatile("s_waitcnt vmcnt(8)\n\ts_barrier" ::: "memory");
        // issue group 1: B frag 0,1 + A frag 0,1 (oldest 8)
        i32x4 b00 = ldsr(baseB[cur] + offB[0] + s0), b01 = ldsr(baseB[cur] + offB[0] + s1);
        i32x4 b10 = ldsr(baseB[cur] + offB[1] + s0), b11 = ldsr(baseB[cur] + offB[1] + s1);
        i32x4 a00 = ldsr(baseA[cur] + offA[0] + s0), a01 = ldsr(baseA[cur] + offA[0] + s1);
        i32x4 a10 = ldsr(baseA[cur] + offA[1] + s0), a11 = ldsr(baseA[cur] + offA[1] + s1);
        // issue group 2: B frag 2,3 + A frag 2,3
        i32x4 b20 = ldsr(baseB[cur] + offB[2] + s0), b21 = ldsr(baseB[cur] + offB[2] + s1);
        i32x4 b30 = ldsr(baseB[cur] + offB[3] + s0), b31 = ldsr(baseB[cur] + offB[3] + s1);
        i32x4 a20 = ldsr(baseA[cur] + offA[2] + s0), a21 = ldsr(baseA[cur] + offA[2] + s1);
        i32x4 a30 = ldsr(baseA[cur] + offA[3] + s0), a31 = ldsr(baseA[cur] + offA[3] + s1);
        union F { i32x4 h[2]; i32x8 v; };
        F ua0, ua1, ua2, ua3, ub0, ub1, ub2, ub3;
        // ---- cluster 0: needs group 1 only (8 in flight = group 2) ----
        asm volatile("s_waitcnt lgkmcnt(8)"
                     : "+v"(b00), "+v"(b01), "+v"(b10), "+v"(b11),
                       "+v"(a00), "+v"(a01), "+v"(a10), "+v"(a11));
        __builtin_amdgcn_sched_barrier(0);
        ub0.h[0] = b00; ub0.h[1] = b01; ub1.h[0] = b10; ub1.h[1] = b11;
        ua0.h[0] = a00; ua0.h[1] = a01; ua1.h[0] = a10; ua1.h[1] = a11;
        __builtin_amdgcn_s_setprio(1);
        acc[0][0] = __builtin_amdgcn_mfma_scale_f32_16x16x128_f8f6f4(ua0.v, ub0.v, acc[0][0], 0, 0, 0, 0x7F7F7F7F, 0, 0x7F7F7F7F);
        acc[0][1] = __builtin_amdgcn_mfma_scale_f32_16x16x128_f8f6f4(ua0.v, ub1.v, acc[0][1], 0, 0, 0, 0x7F7F7F7F, 0, 0x7F7F7F7F);
        acc[1][0] = __builtin_amdgcn_mfma_scale_f32_16x16x128_f8f6f4(ua1.v, ub0.v, acc[1][0], 0, 0, 0, 0x7F7F7F7F, 0, 0x7F7F7F7F);
        acc[1][1] = __builtin_amdgcn_mfma_scale_f32_16x16x128_f8f6f4(ua1.v, ub1.v, acc[1][1], 0, 0, 0, 0x7F7F7F7F, 0, 0x7F7F7F7F);
        __builtin_amdgcn_s_setprio(0);
        // ---- cluster 1: + B frag 2,3 (4 in flight = A frag 2,3) ----
        asm volatile("s_waitcnt lgkmcnt(4)"
                     : "+v"(b20), "+v"(b21), "+v"(b30), "+v"(b31));
        __builtin_amdgcn_sched_barrier(0);
        ub2.h[0] = b20; ub2.h[1] = b21; ub3.h[0] = b30; ub3.h[1] = b31;
        __builtin_amdgcn_s_setprio(1);
        acc[0][2] = __builtin_amdgcn_mfma_scale_f32_16x16x128_f8f6f4(ua0.v, ub2.v, acc[0][2], 0, 0, 0, 0x7F7F7F7F, 0, 0x7F7F7F7F);
        acc[0][3] = __builtin_amdgcn_mfma_scale_f32_16x16x128_f8f6f4(ua0.v, ub3.v, acc[0][3], 0, 0, 0, 0x7F7F7F7F, 0, 0x7F7F7F7F);
        acc[1][2] = __builtin_amdgcn_mfma_scale_f32_16x16x128_f8f6f4(ua1.v, ub2.v, acc[1][2], 0, 0, 0, 0x7F7F7F7F, 0, 0x7F7F7F7F);
        acc[1][3] = __builtin_amdgcn_mfma_scale_f32_16x16x128_f8f6f4(ua1.v, ub3.v, acc[1][3], 0, 0, 0, 0x7F7F7F7F, 0, 0x7F7F7F7F);
        __builtin_amdgcn_s_setprio(0);
        // ---- all reads landed: release the buffer (WAR barrier), then cluster 2/3
        // runs register-only in the barrier shadow ----
        asm volatile("s_waitcnt lgkmcnt(0)"
                     : "+v"(a20), "+v"(a21), "+v"(a30), "+v"(a31));
        __builtin_amdgcn_sched_barrier(0);
        asm volatile("s_barrier" ::: "memory");
        __builtin_amdgcn_sched_barrier(0);
        ua2.h[0] = a20; ua2.h[1] = a21; ua3.h[0] = a30; ua3.h[1] = a31;
        __builtin_amdgcn_s_setprio(1);
        acc[2][0] = __builtin_amdgcn_mfma_scale_f32_16x16x128_f8f6f4(ua2.v, ub0.v, acc[2][0], 0, 0, 0, 0x7F7F7F7F, 0, 0x7F7F7F7F);
        acc[2][1] = __builtin_amdgcn_mfma_scale_f32_16x16x128_f8f6f4(ua2.v, ub1.v, acc[2][1], 0, 0, 0, 0x7F7F7F7F, 0, 0x7F7F7F7F);
        acc[2][2] = __builtin_amdgcn_mfma_scale_f32_16x16x128_f8f6f4(ua2.v, ub2.v, acc[2][2], 0, 0, 0, 0x7F7F7F7F, 0, 0x7F7F7F7F);
        acc[2][3] = __builtin_amdgcn_mfma_scale_f32_16x16x128_f8f6f4(ua2.v, ub3.v, acc[2][3], 0, 0, 0, 0x7F7F7F7F, 0, 0x7F7F7F7F);
        acc[3][0] = __builtin_amdgcn_mfma_scale_f32_16x16x128_f8f6f4(ua3.v, ub0.v, acc[3][0], 0, 0, 0, 0x7F7F7F7F, 0, 0x7F7F7F7F);
        acc[3][1] = __builtin_amdgcn_mfma_scale_f32_16x16x128_f8f6f4(ua3.v, ub1.v, acc[3][1], 0, 0, 0, 0x7F7F7F7F, 0, 0x7F7F7F7F);
        acc[3][2] = __builtin_amdgcn_mfma_scale_f32_16x16x128_f8f6f4(ua3.v, ub2.v, acc[3][2], 0, 0, 0, 0x7F7F7F7F, 0, 0x7F7F7F7F);
        acc[3][3] = __builtin_amdgcn_mfma_scale_f32_16x16x128_f8f6f4(ua3.v, ub3.v, acc[3][3], 0, 0, 0, 0x7F7F7F7F, 0, 0x7F7F7F7F);
        __builtin_amdgcn_s_setprio(0);
    }
}

// ---------------- fused dual-GEMM + kernel epilogue (no Gram materialization) ----
// R2: static LDS trimmed to EXACTLY 65536 B (was 68096) so two blocks fit a
// 128 KiB pool -> target 2 blocks/CU, 2 waves/SIMD. sq values now read straight
// from global in the epilogue (L2-hot, runs once); cross-wave reduction reuses
// the dead smem[0] buffer after draining GEMM2's dummy tail prefetch.
__global__ __launch_bounds__(256, 2) void jmmd_fused(
    const uint8_t* __restrict__ t1f8, const uint8_t* __restrict__ t2f8,
    const float* __restrict__ sq1, const float* __restrict__ sq2,
    const float* __restrict__ cv, float* __restrict__ out) {
    __shared__ alignas(16) uint8_t smem[4][16384];   // A0,B0,A1,B1 — exactly 64 KiB
    int tid = threadIdx.x;
    int ti = 0, r = blockIdx.x;
    while (r >= TT - ti) { r -= TT - ti; ++ti; }
    int tj = ti + r;
    int i0 = ti * 128, j0 = tj * 128;
    int lane = tid & 63, wv = tid >> 6;
    int wm = wv >> 1, wn = wv & 1, lm = lane & 15, quad = lane >> 4;
    f32x4 acc1[4][4] = {};
    f32x4 acc2[4][4] = {};
    gemm_mx_pipe(t1f8 + (size_t)i0 * D1, t1f8 + (size_t)j0 * D1, D1,
                 smem[0], smem[1], smem[2], smem[3], acc1, wv, lane, wm, wn, lm, quad);
    // drain dummy prefetch + sync before re-priming the same buffers
    asm volatile("s_waitcnt vmcnt(0)\n\ts_barrier" ::: "memory");
    gemm_mx_pipe(t2f8 + (size_t)i0 * D2, t2f8 + (size_t)j0 * D2, D2,
                 smem[0], smem[1], smem[2], smem[3], acc2, wv, lane, wm, wn, lm, quad);
    // GEMM2's last iteration issued a dummy prefetch into smem[0]/smem[1] —
    // drain it (per-wave vmcnt(0), then all-waves barrier) before reusing smem[0].
    asm volatile("s_waitcnt vmcnt(0)" ::: "memory");
    __syncthreads();
    float c1 = cv[0], c2 = cv[1];
    float local = 0.f;
    bool diag = (ti == tj);
#pragma unroll
    for (int mi = 0; mi < 4; ++mi) {
        int rbase = wm * 64 + mi * 16 + quad * 4;
#pragma unroll
        for (int ni = 0; ni < 4; ++ni) {
            int col = wn * 64 + ni * 16 + lm;
            float sb1 = sq1[j0 + col], sb2 = sq2[j0 + col];
#pragma unroll
            for (int rr = 0; rr < 4; ++rr) {
                int row = rbase + rr;
                float l2a = fmaxf(sq1[i0 + row] + sb1 - 2.f * acc1[mi][ni][rr], 0.f);
                float l2b = fmaxf(sq2[i0 + row] + sb2 - 2.f * acc2[mi][ni][rr], 0.f);
                float t1 = __builtin_amdgcn_exp2f(-l2a * c1);
                float k1 = t1; float u1 = t1 * t1; k1 += u1; u1 *= u1; k1 += u1; u1 *= u1; k1 += u1; u1 *= u1; k1 += u1;
                float t2 = __builtin_amdgcn_exp2f(-l2b * c2);
                float k2 = t2; float u2 = t2 * t2; k2 += u2; u2 *= u2; k2 += u2; u2 *= u2; k2 += u2; u2 *= u2; k2 += u2;
                float v = k1 * k2;
                if (diag && (row == col)) v = 0.f;
                local += v;
            }
        }
    }
    for (int o = 32; o; o >>= 1) local += __shfl_down(local, o);
    float* redp = (float*)smem[0];   // buffers dead past this point
    if (lane == 0) redp[wv] = local;
    __syncthreads();
    if (tid == 0) {
        bool same = (i0 < BHALF) == (j0 < BHALF);
        float w = same ? (1.0f / ((float)BHALF * (float)(BHALF - 1)))
                       : (-1.0f / ((float)BHALF * (float)BHALF));
        if (!diag) w *= 2.f;
        atomicAdd(out, (redp[0] + redp[1] + redp[2] + redp[3]) * w);
    }
}

extern "C" void kernel_launch(void* const* d_in, const int* in_sizes, int n_in,
                              void* d_out, int out_size, void* d_ws, size_t ws_size,
                              hipStream_t stream) {
    const float* z1s = (const float*)d_in[0];
    const float* z1t = (const float*)d_in[1];
    const float* z2s = (const float*)d_in[2];
    const float* z2t = (const float*)d_in[3];
    float* out = (float*)d_out;

    float* ws = (float*)d_ws;
    float* sq1 = ws;              // 4096
    float* sq2 = ws + 4096;       // 4096
    float* s1  = ws + 8192;       // 4096
    float* s2  = ws + 12288;      // 2048
    float* acc = ws + 14336;      // [2]=c1 [3]=c2
    uint8_t* t1f8 = (uint8_t*)(ws + 14344);            // 16B-aligned
    uint8_t* t2f8 = t1f8 + (size_t)NTOT * D1;

    prep_kernel<<<8192, 256, 0, stream>>>(z1s, z1t, z2s, z2t, sq1, sq2, t1f8, t2f8, s1, s2);
    colsum_fp8_kernel<<<384, 256, 0, stream>>>(t1f8, t2f8, s1, s2);
    finalize_kernel<<<1, 256, 0, stream>>>(s1, s2, sq1, sq2, acc, out);
    jmmd_fused<<<NTILES, 256, 0, stream>>>(t1f8, t2f8, sq1, sq2, acc + 2, out);
}